// Round 1
// baseline (848.474 us; speedup 1.0000x reference)
//
#include <hip/hip_runtime.h>

#define Bc 16
#define Nc 512
#define Dc 768
#define Hc 12
#define Ec 8
#define HDc 64

constexpr int TS = 64;   // output tile 64x64
constexpr int KT = 16;   // k-step

// ---------------- gating fold: Wc[b] = sum_e g[b,e] * W[e] ----------------
__global__ __launch_bounds__(256) void combine_w_kernel(const float* __restrict__ g,
                                                        const float* __restrict__ W,
                                                        float* __restrict__ Wc) {
    __shared__ float gs[Bc * Ec];
    int tid = threadIdx.x;
    if (tid < Bc * Ec) gs[tid] = g[tid];
    __syncthreads();
    const int P = Dc * Dc / 4;
    int p = blockIdx.x * blockDim.x + tid;
    if (p >= P) return;
    float4 w[Ec];
#pragma unroll
    for (int e = 0; e < Ec; ++e) w[e] = ((const float4*)W)[(size_t)e * P + p];
#pragma unroll
    for (int b = 0; b < Bc; ++b) {
        float4 acc = {0.f, 0.f, 0.f, 0.f};
#pragma unroll
        for (int e = 0; e < Ec; ++e) {
            float ge = gs[b * Ec + e];
            acc.x += ge * w[e].x; acc.y += ge * w[e].y;
            acc.z += ge * w[e].z; acc.w += ge * w[e].w;
        }
        ((float4*)Wc)[(size_t)b * P + p] = acc;
    }
}

__global__ __launch_bounds__(256) void combine_b_kernel(const float* __restrict__ g,
                                                        const float* __restrict__ bvec,
                                                        float* __restrict__ bc) {
    int i = blockIdx.x * blockDim.x + threadIdx.x;
    if (i >= Bc * Dc) return;
    int b = i / Dc, o = i - b * Dc;
    float acc = 0.f;
#pragma unroll
    for (int e = 0; e < Ec; ++e) acc += g[b * Ec + e] * bvec[e * Dc + o];
    bc[i] = acc;
}

// ---------------- generic NT GEMM: C = scale*(A * B^T) + bias ----------------
// mode 0: proj   (z = batch)   A=x[z], B=Wc[z], C=QKV[z], bias=bc[z]
// mode 1: scores (z = b*H+h)   A=Q[b]+h*HD, B=K[b]+h*HD, C=scores[z]
// mode 2: outproj(z = batch)   A=ctx[z], B=Wo, C=out[z], bias=bo
__global__ __launch_bounds__(256) void gemm_nt_kernel(const float* __restrict__ A,
                                                      const float* __restrict__ Bm,
                                                      float* __restrict__ C,
                                                      const float* __restrict__ bias,
                                                      int lda, int ldb, int ldc, int K,
                                                      float scale, int mode) {
    __shared__ __align__(16) float As[KT][TS];
    __shared__ __align__(16) float Bs[KT][TS];
    int tid = threadIdx.x;
    int tx = tid & 15, ty = tid >> 4;
    int n0 = blockIdx.x * TS, m0 = blockIdx.y * TS;
    int z = blockIdx.z;
    size_t aOff, bOff, cOff; int biasOff = 0;
    if (mode == 0) {
        aOff = (size_t)z * Nc * Dc; bOff = (size_t)z * Dc * Dc;
        cOff = (size_t)z * Nc * Dc; biasOff = z * Dc;
    } else if (mode == 1) {
        int b = z / Hc, h = z - b * Hc;
        aOff = (size_t)b * Nc * Dc + h * HDc; bOff = aOff;
        cOff = (size_t)z * Nc * Nc;
    } else {
        aOff = (size_t)z * Nc * Dc; bOff = 0;
        cOff = (size_t)z * Nc * Dc;
    }
    const float* Ab = A + aOff;
    const float* Bb = Bm + bOff;

    int lm = tid & 63;   // row within tile (loader)
    int lk = tid >> 6;   // float4 index along k (0..3)

    float acc[4][4] = {};
    for (int k0 = 0; k0 < K; k0 += KT) {
        float4 av = *(const float4*)&Ab[(size_t)(m0 + lm) * lda + k0 + lk * 4];
        float4 bv = *(const float4*)&Bb[(size_t)(n0 + lm) * ldb + k0 + lk * 4];
        As[lk * 4 + 0][lm] = av.x; As[lk * 4 + 1][lm] = av.y;
        As[lk * 4 + 2][lm] = av.z; As[lk * 4 + 3][lm] = av.w;
        Bs[lk * 4 + 0][lm] = bv.x; Bs[lk * 4 + 1][lm] = bv.y;
        Bs[lk * 4 + 2][lm] = bv.z; Bs[lk * 4 + 3][lm] = bv.w;
        __syncthreads();
#pragma unroll
        for (int k = 0; k < KT; ++k) {
            float4 a4 = *(const float4*)&As[k][ty * 4];
            float4 b4 = *(const float4*)&Bs[k][tx * 4];
            float am[4] = {a4.x, a4.y, a4.z, a4.w};
            float bm[4] = {b4.x, b4.y, b4.z, b4.w};
#pragma unroll
            for (int i = 0; i < 4; ++i)
#pragma unroll
                for (int j = 0; j < 4; ++j) acc[i][j] += am[i] * bm[j];
        }
        __syncthreads();
    }
    float bvals[4] = {0.f, 0.f, 0.f, 0.f};
    if (bias) {
#pragma unroll
        for (int j = 0; j < 4; ++j) bvals[j] = bias[biasOff + n0 + tx * 4 + j];
    }
#pragma unroll
    for (int i = 0; i < 4; ++i) {
        float4 o;
        o.x = acc[i][0] * scale + bvals[0];
        o.y = acc[i][1] * scale + bvals[1];
        o.z = acc[i][2] * scale + bvals[2];
        o.w = acc[i][3] * scale + bvals[3];
        *(float4*)&C[cOff + (size_t)(m0 + ty * 4 + i) * ldc + n0 + tx * 4] = o;
    }
}

// ---------------- NN GEMM: ctx[b,:,h*HD:] = attn[z] * V[b][:, h*HD:] ----------------
__global__ __launch_bounds__(256) void gemm_nn_kernel(const float* __restrict__ A,
                                                      const float* __restrict__ Bm,
                                                      float* __restrict__ C,
                                                      int lda, int ldb, int ldc, int K) {
    __shared__ __align__(16) float As[KT][TS];
    __shared__ __align__(16) float Bs[KT][TS];
    int tid = threadIdx.x;
    int tx = tid & 15, ty = tid >> 4;
    int n0 = blockIdx.x * TS, m0 = blockIdx.y * TS;
    int z = blockIdx.z;
    int b = z / Hc, h = z - b * Hc;
    const float* Ab = A + (size_t)z * Nc * Nc;
    const float* Bb = Bm + (size_t)b * Nc * Dc + h * HDc;
    float* Cb = C + (size_t)b * Nc * Dc + h * HDc;

    int lm = tid & 63;  // A loader: row in tile
    int lk = tid >> 6;  // A loader: float4 along k
    int bk = tid >> 4;  // B loader: k row (0..15)
    int bn = tid & 15;  // B loader: float4 along n

    float acc[4][4] = {};
    for (int k0 = 0; k0 < K; k0 += KT) {
        float4 av = *(const float4*)&Ab[(size_t)(m0 + lm) * lda + k0 + lk * 4];
        float4 bv = *(const float4*)&Bb[(size_t)(k0 + bk) * ldb + n0 + bn * 4];
        As[lk * 4 + 0][lm] = av.x; As[lk * 4 + 1][lm] = av.y;
        As[lk * 4 + 2][lm] = av.z; As[lk * 4 + 3][lm] = av.w;
        *(float4*)&Bs[bk][bn * 4] = bv;
        __syncthreads();
#pragma unroll
        for (int k = 0; k < KT; ++k) {
            float4 a4 = *(const float4*)&As[k][ty * 4];
            float4 b4 = *(const float4*)&Bs[k][tx * 4];
            float am[4] = {a4.x, a4.y, a4.z, a4.w};
            float bm[4] = {b4.x, b4.y, b4.z, b4.w};
#pragma unroll
            for (int i = 0; i < 4; ++i)
#pragma unroll
                for (int j = 0; j < 4; ++j) acc[i][j] += am[i] * bm[j];
        }
        __syncthreads();
    }
#pragma unroll
    for (int i = 0; i < 4; ++i) {
        float4 o = {acc[i][0], acc[i][1], acc[i][2], acc[i][3]};
        *(float4*)&Cb[(size_t)(m0 + ty * 4 + i) * ldc + n0 + tx * 4] = o;
    }
}

// ---------------- in-place row softmax over attn [B*H*N rows of length N] ----------------
__global__ __launch_bounds__(256) void softmax_kernel(float* __restrict__ attn) {
    int gw = (int)((blockIdx.x * 256 + threadIdx.x) >> 6); // one wave per row
    int lane = threadIdx.x & 63;
    float* row = attn + (size_t)gw * Nc;
    float4 v0 = ((float4*)row)[lane * 2];
    float4 v1 = ((float4*)row)[lane * 2 + 1];
    float m = fmaxf(fmaxf(fmaxf(v0.x, v0.y), fmaxf(v0.z, v0.w)),
                    fmaxf(fmaxf(v1.x, v1.y), fmaxf(v1.z, v1.w)));
#pragma unroll
    for (int off = 32; off >= 1; off >>= 1) m = fmaxf(m, __shfl_xor(m, off));
    v0.x = __expf(v0.x - m); v0.y = __expf(v0.y - m);
    v0.z = __expf(v0.z - m); v0.w = __expf(v0.w - m);
    v1.x = __expf(v1.x - m); v1.y = __expf(v1.y - m);
    v1.z = __expf(v1.z - m); v1.w = __expf(v1.w - m);
    float s = v0.x + v0.y + v0.z + v0.w + v1.x + v1.y + v1.z + v1.w;
#pragma unroll
    for (int off = 32; off >= 1; off >>= 1) s += __shfl_xor(s, off);
    float inv = 1.0f / s;
    v0.x *= inv; v0.y *= inv; v0.z *= inv; v0.w *= inv;
    v1.x *= inv; v1.y *= inv; v1.z *= inv; v1.w *= inv;
    ((float4*)row)[lane * 2] = v0;
    ((float4*)row)[lane * 2 + 1] = v1;
}

extern "C" void kernel_launch(void* const* d_in, const int* in_sizes, int n_in,
                              void* d_out, int out_size, void* d_ws, size_t ws_size,
                              hipStream_t stream) {
    (void)in_sizes; (void)n_in; (void)out_size; (void)ws_size;
    const float* x  = (const float*)d_in[0];
    const float* g  = (const float*)d_in[1];
    const float* Wq = (const float*)d_in[2];
    const float* bq = (const float*)d_in[3];
    const float* Wk = (const float*)d_in[4];
    const float* bk = (const float*)d_in[5];
    const float* Wv = (const float*)d_in[6];
    const float* bv = (const float*)d_in[7];
    const float* Wo = (const float*)d_in[8];
    const float* bo = (const float*)d_in[9];

    float* out  = (float*)d_out;
    float* attn = out + (size_t)Bc * Nc * Dc;

    float* ws = (float*)d_ws;
    float* Wc = ws;                                 // B*D*D
    float* bc = Wc + (size_t)Bc * Dc * Dc;          // B*D
    float* Q  = bc + (size_t)Bc * Dc;               // B*N*D
    float* Kt = Q + (size_t)Bc * Nc * Dc;           // B*N*D
    float* V  = Kt + (size_t)Bc * Nc * Dc;          // B*N*D
    float* ctx = ws;                                // reuse Wc region (B*N*D fits)

    dim3 blk(256);
    const float* Ws[3] = {Wq, Wk, Wv};
    const float* bs[3] = {bq, bk, bv};
    float* outs[3] = {Q, Kt, V};
    for (int t = 0; t < 3; ++t) {
        combine_w_kernel<<<(Dc * Dc / 4 + 255) / 256, blk, 0, stream>>>(g, Ws[t], Wc);
        combine_b_kernel<<<(Bc * Dc + 255) / 256, blk, 0, stream>>>(g, bs[t], bc);
        gemm_nt_kernel<<<dim3(Dc / TS, Nc / TS, Bc), blk, 0, stream>>>(
            x, Wc, outs[t], bc, Dc, Dc, Dc, Dc, 1.0f, 0);
    }
    // scores -> attn region (raw), then softmax in place
    gemm_nt_kernel<<<dim3(Nc / TS, Nc / TS, Bc * Hc), blk, 0, stream>>>(
        Q, Kt, attn, nullptr, Dc, Dc, Nc, HDc, 0.125f, 1);
    softmax_kernel<<<(Bc * Hc * Nc) / 4, blk, 0, stream>>>(attn);
    // ctx = attn @ V  (written as [B,N,D] directly)
    gemm_nn_kernel<<<dim3(1, Nc / TS, Bc * Hc), blk, 0, stream>>>(
        attn, V, ctx, Nc, Dc, Dc, Nc);
    // out = ctx @ Wo^T + bo
    gemm_nt_kernel<<<dim3(Dc / TS, Nc / TS, Bc), blk, 0, stream>>>(
        ctx, Wo, out, bo, Dc, Dc, Dc, Dc, 1.0f, 2);
}

// Round 2
// 287.792 us; speedup vs baseline: 2.9482x; 2.9482x over previous
//
#include <hip/hip_runtime.h>
#include <hip/hip_bf16.h>

#define Bc 16
#define Nc 512
#define Dc 768
#define Hc 12
#define Ec 8
#define HDc 64
#define D3 (3 * Dc)   // 2304

typedef __hip_bfloat16 bf16;
typedef short bf16x8 __attribute__((ext_vector_type(8)));     // 8 bf16, 4 VGPR
typedef float f32x4 __attribute__((ext_vector_type(4)));
typedef unsigned short u16x4 __attribute__((ext_vector_type(4)));

__device__ __forceinline__ unsigned short f2bf(float f) {
    union { __hip_bfloat16 h; unsigned short u; } cv;
    cv.h = __float2bfloat16(f);
    return cv.u;
}

__device__ __forceinline__ void gload16(const void* src, void* ldsDst) {
    __builtin_amdgcn_global_load_lds((const __attribute__((address_space(1))) void*)src,
                                     (__attribute__((address_space(3))) void*)ldsDst,
                                     16, 0, 0);
}

// ---------------- cast f32 -> bf16, 8 elems/thread ----------------
__global__ __launch_bounds__(256) void cast_bf16_kernel(const float* __restrict__ in,
                                                        bf16* __restrict__ out, int n8) {
    int i = blockIdx.x * 256 + threadIdx.x;
    if (i >= n8) return;
    f32x4 a = ((const f32x4*)in)[i * 2];
    f32x4 b = ((const f32x4*)in)[i * 2 + 1];
    unsigned short t[8];
#pragma unroll
    for (int j = 0; j < 4; ++j) { t[j] = f2bf(a[j]); t[4 + j] = f2bf(b[j]); }
    ((bf16x8*)out)[i] = *(bf16x8*)t;
}

// ---------------- gating fold: Wc[b][t*768+o][i] = sum_e g[b,e] W[e][o][i] (bf16 out) ----------------
__global__ __launch_bounds__(256) void combine_w_kernel(const float* __restrict__ g,
                                                        const float* __restrict__ W,
                                                        bf16* __restrict__ Wc, int t) {
    __shared__ float gs[Bc * Ec];
    int tid = threadIdx.x;
    if (tid < Bc * Ec) gs[tid] = g[tid];
    __syncthreads();
    const int P = Dc * Dc / 4;   // float4 positions
    int p = blockIdx.x * 256 + tid;
    if (p >= P) return;
    f32x4 w[Ec];
#pragma unroll
    for (int e = 0; e < Ec; ++e) w[e] = ((const f32x4*)W)[(size_t)e * P + p];
    int o = p / (Dc / 4), i4 = p - o * (Dc / 4);
#pragma unroll
    for (int b = 0; b < Bc; ++b) {
        f32x4 acc = {0.f, 0.f, 0.f, 0.f};
#pragma unroll
        for (int e = 0; e < Ec; ++e) {
            float ge = gs[b * Ec + e];
            acc[0] += ge * w[e][0]; acc[1] += ge * w[e][1];
            acc[2] += ge * w[e][2]; acc[3] += ge * w[e][3];
        }
        u16x4 ov;
#pragma unroll
        for (int j = 0; j < 4; ++j) ov[j] = f2bf(acc[j]);
        *(u16x4*)&Wc[((size_t)b * D3 + t * Dc + o) * Dc + i4 * 4] = ov;
    }
}

__global__ __launch_bounds__(256) void combine_b_kernel(const float* __restrict__ g,
                                                        const float* __restrict__ bvec,
                                                        float* __restrict__ bc, int t) {
    int i = blockIdx.x * 256 + threadIdx.x;
    if (i >= Bc * Dc) return;
    int b = i / Dc, o = i - b * Dc;
    float acc = 0.f;
#pragma unroll
    for (int e = 0; e < Ec; ++e) acc += g[b * Ec + e] * bvec[e * Dc + o];
    bc[(size_t)b * D3 + t * Dc + o] = acc;
}

// ---------------- bf16 MFMA NT GEMM: C[z] = A[z] * B[z]^T (+ bias) ----------------
// A: [M][lda] (bf16, or f32 converted on the fly), B: [N][ldb] bf16 row-major.
// 256 threads = 4 waves (2x2), tile BM x BN, BK=32, 16x16x32 MFMA.
template<int BM, int BN, bool A_F32, bool OUT_BF16, bool BIAS, bool CTX_C>
__global__ __launch_bounds__(256) void gemm_mfma(const void* __restrict__ Ain,
                                                 const bf16* __restrict__ Bin,
                                                 void* __restrict__ Cout,
                                                 const float* __restrict__ bias,
                                                 int lda, int ldb, int ldc, int K,
                                                 long sA, long sB, long sC, int sBias) {
    constexpr int AROW = A_F32 ? 128 : 64;       // LDS bytes per A-tile row (32 elems)
    constexpr int A_LDS = BM * AROW;
    constexpr int B_LDS = BN * 64;
    __shared__ __align__(16) char lds[A_LDS + B_LDS];
    char* ldsA = lds;
    char* ldsB = lds + A_LDS;

    const int tid = threadIdx.x;
    const int lane = tid & 63;
    const int wave = tid >> 6;
    const int wr = wave >> 1, wc = wave & 1;
    constexpr int TM = BM / 32;
    constexpr int TN = BN / 32;
    const int m0 = blockIdx.y * BM;
    const int n0 = blockIdx.x * BN;
    const int z = blockIdx.z;
    const int mbase = wr * (BM / 2);
    const int nbase = wc * (BN / 2);

    const char* Ab = (const char*)Ain + (size_t)z * sA * (A_F32 ? 4 : 2);
    const bf16* Bb = Bin + (size_t)z * sB;

    f32x4 acc[TM][TN];
#pragma unroll
    for (int m = 0; m < TM; ++m)
#pragma unroll
        for (int n = 0; n < TN; ++n) acc[m][n] = f32x4{0.f, 0.f, 0.f, 0.f};

    constexpr int ACH = A_F32 ? BM / 32 : BM / 64;  // LDS chunks (1024B) per wave
    constexpr int BCH = BN / 64;

    for (int k0 = 0; k0 < K; k0 += 32) {
        // ---- stage A tile ----
#pragma unroll
        for (int c = 0; c < ACH; ++c) {
            int q = wave * ACH + c;
            if constexpr (A_F32) {
                int row = q * 8 + (lane >> 3);
                int sl = (lane & 7) ^ (row & 7);   // source pre-swizzle
                const char* src = Ab + ((size_t)(m0 + row) * lda + k0 + sl * 4) * 4;
                gload16(src, ldsA + q * 1024);
            } else {
                int row = q * 16 + (lane >> 2);
                int sl = (lane & 3) ^ (row & 3);
                const char* src = Ab + ((size_t)(m0 + row) * lda + k0 + sl * 8) * 2;
                gload16(src, ldsA + q * 1024);
            }
        }
        // ---- stage B tile ----
#pragma unroll
        for (int c = 0; c < BCH; ++c) {
            int q = wave * BCH + c;
            int row = q * 16 + (lane >> 2);
            int sl = (lane & 3) ^ (row & 3);
            const bf16* src = Bb + (size_t)(n0 + row) * ldb + k0 + sl * 8;
            gload16(src, ldsB + q * 1024);
        }
        __syncthreads();

        bf16x8 af[TM], bfr[TN];
#pragma unroll
        for (int m = 0; m < TM; ++m) {
            int r = mbase + m * 16 + (lane & 15);
            if constexpr (A_F32) {
                int s0 = ((lane >> 4) * 2) ^ (lane & 7);
                int s1 = ((lane >> 4) * 2 + 1) ^ (lane & 7);
                f32x4 f0 = *(const f32x4*)(ldsA + r * 128 + s0 * 16);
                f32x4 f1 = *(const f32x4*)(ldsA + r * 128 + s1 * 16);
                unsigned short t[8];
#pragma unroll
                for (int j = 0; j < 4; ++j) { t[j] = f2bf(f0[j]); t[4 + j] = f2bf(f1[j]); }
                af[m] = *(bf16x8*)t;
            } else {
                int sp = (lane >> 4) ^ (lane & 3);
                af[m] = *(const bf16x8*)(ldsA + r * 64 + sp * 16);
            }
        }
#pragma unroll
        for (int n = 0; n < TN; ++n) {
            int r = nbase + n * 16 + (lane & 15);
            int sp = (lane >> 4) ^ (lane & 3);
            bfr[n] = *(const bf16x8*)(ldsB + r * 64 + sp * 16);
        }
#pragma unroll
        for (int m = 0; m < TM; ++m)
#pragma unroll
            for (int n = 0; n < TN; ++n)
                acc[m][n] = __builtin_amdgcn_mfma_f32_16x16x32_bf16(af[m], bfr[n], acc[m][n], 0, 0, 0);
        __syncthreads();
    }

    // ---- epilogue ----
    size_t cOff;
    if constexpr (CTX_C) cOff = (size_t)(z / Hc) * sC + (size_t)(z % Hc) * HDc;
    else cOff = (size_t)z * sC;
#pragma unroll
    for (int n = 0; n < TN; ++n) {
        int col = n0 + nbase + n * 16 + (lane & 15);
        float bv = 0.f;
        if constexpr (BIAS) bv = bias[(size_t)z * sBias + col];
#pragma unroll
        for (int m = 0; m < TM; ++m) {
            int row = m0 + mbase + m * 16 + (lane >> 4) * 4;
#pragma unroll
            for (int r = 0; r < 4; ++r) {
                float val = acc[m][n][r] + bv;
                if constexpr (OUT_BF16)
                    ((bf16*)Cout)[cOff + (size_t)(row + r) * ldc + col] = __float2bfloat16(val);
                else
                    ((float*)Cout)[cOff + (size_t)(row + r) * ldc + col] = val;
            }
        }
    }
}

// ---------------- fused scores + softmax: attn[z] = softmax(Q K^T / 8) ----------------
// grid (8 q-tiles, 192 bh). Block 256 = 4 waves; each wave owns 16 q-rows x all 512 k.
__global__ __launch_bounds__(256) void scores_softmax_kernel(const bf16* __restrict__ QKV,
                                                             float* __restrict__ attn) {
    int z = blockIdx.y;
    int b = z / Hc, h = z - b * Hc;
    int wave = threadIdx.x >> 6, lane = threadIdx.x & 63;
    int qbase = blockIdx.x * 64 + wave * 16;
    const bf16* Qb = QKV + (size_t)b * Nc * D3 + h * HDc;
    const bf16* Kb = Qb + Dc;
    int koff = (lane >> 4) * 8;

    bf16x8 qf0 = *(const bf16x8*)(Qb + (size_t)(qbase + (lane & 15)) * D3 + koff);
    bf16x8 qf1 = *(const bf16x8*)(Qb + (size_t)(qbase + (lane & 15)) * D3 + 32 + koff);

    f32x4 acc[32];
#pragma unroll
    for (int n = 0; n < 32; ++n) {
        int krow = n * 16 + (lane & 15);
        bf16x8 k0 = *(const bf16x8*)(Kb + (size_t)krow * D3 + koff);
        bf16x8 k1 = *(const bf16x8*)(Kb + (size_t)krow * D3 + 32 + koff);
        f32x4 a = {0.f, 0.f, 0.f, 0.f};
        a = __builtin_amdgcn_mfma_f32_16x16x32_bf16(qf0, k0, a, 0, 0, 0);
        a = __builtin_amdgcn_mfma_f32_16x16x32_bf16(qf1, k1, a, 0, 0, 0);
        acc[n] = a;
    }

    const float sc = 0.125f;
    float mx[4] = {-1e30f, -1e30f, -1e30f, -1e30f};
#pragma unroll
    for (int n = 0; n < 32; ++n)
#pragma unroll
        for (int r = 0; r < 4; ++r) {
            acc[n][r] *= sc;
            mx[r] = fmaxf(mx[r], acc[n][r]);
        }
#pragma unroll
    for (int off = 8; off >= 1; off >>= 1)
#pragma unroll
        for (int r = 0; r < 4; ++r) mx[r] = fmaxf(mx[r], __shfl_xor(mx[r], off));

    float sum[4] = {0.f, 0.f, 0.f, 0.f};
#pragma unroll
    for (int n = 0; n < 32; ++n)
#pragma unroll
        for (int r = 0; r < 4; ++r) {
            float e = __expf(acc[n][r] - mx[r]);
            acc[n][r] = e;
            sum[r] += e;
        }
#pragma unroll
    for (int off = 8; off >= 1; off >>= 1)
#pragma unroll
        for (int r = 0; r < 4; ++r) sum[r] += __shfl_xor(sum[r], off);
    float inv[4];
#pragma unroll
    for (int r = 0; r < 4; ++r) inv[r] = 1.0f / sum[r];

    float* arow = attn + (size_t)z * Nc * Nc;
    int orow = qbase + (lane >> 4) * 4;
    int ocol = lane & 15;
#pragma unroll
    for (int n = 0; n < 32; ++n)
#pragma unroll
        for (int r = 0; r < 4; ++r)
            arow[(size_t)(orow + r) * Nc + n * 16 + ocol] = acc[n][r] * inv[r];
}

// ---------------- Vt[z][d][k] = V[b][k][1536 + h*64 + d] (bf16) ----------------
__global__ __launch_bounds__(256) void transpose_v_kernel(const bf16* __restrict__ QKV,
                                                          bf16* __restrict__ Vt) {
    int z = blockIdx.y;
    int b = z / Hc, h = z - b * Hc;
    int k0 = blockIdx.x * 64;
    __shared__ bf16 t[64][72];
    const bf16* src = QKV + ((size_t)b * Nc + k0) * D3 + 2 * Dc + h * HDc;
#pragma unroll
    for (int it = 0; it < 2; ++it) {
        int idx = it * 256 + threadIdx.x;   // 0..511
        int r = idx >> 3, cg = idx & 7;
        bf16x8 v = *(const bf16x8*)(src + (size_t)r * D3 + cg * 8);
#pragma unroll
        for (int j = 0; j < 8; ++j) t[r][cg * 8 + j] = ((const bf16*)&v)[j];
    }
    __syncthreads();
    bf16* dst = Vt + (size_t)z * HDc * Nc + k0;
#pragma unroll
    for (int it = 0; it < 2; ++it) {
        int idx = it * 256 + threadIdx.x;
        int d = idx >> 3, kg = idx & 7;
        bf16 tmp[8];
#pragma unroll
        for (int j = 0; j < 8; ++j) tmp[j] = t[kg * 8 + j][d];
        *(bf16x8*)(dst + (size_t)d * Nc + kg * 8) = *(bf16x8*)tmp;
    }
}

extern "C" void kernel_launch(void* const* d_in, const int* in_sizes, int n_in,
                              void* d_out, int out_size, void* d_ws, size_t ws_size,
                              hipStream_t stream) {
    (void)in_sizes; (void)n_in; (void)out_size; (void)ws_size;
    const float* x  = (const float*)d_in[0];
    const float* g  = (const float*)d_in[1];
    const float* Wq = (const float*)d_in[2];
    const float* bq = (const float*)d_in[3];
    const float* Wk = (const float*)d_in[4];
    const float* bk = (const float*)d_in[5];
    const float* Wv = (const float*)d_in[6];
    const float* bv = (const float*)d_in[7];
    const float* Wo = (const float*)d_in[8];
    const float* bo = (const float*)d_in[9];

    float* out  = (float*)d_out;
    float* attn = out + (size_t)Bc * Nc * Dc;

    // workspace layout (bytes): x_bf | Wo_bf | bc | QKV | R{Wc -> Vt,ctx}
    char* w = (char*)d_ws;
    bf16* x_bf  = (bf16*)w;                              // 16*512*768
    bf16* Wo_bf = x_bf + (size_t)Bc * Nc * Dc;           // 768*768
    float* bc   = (float*)(Wo_bf + (size_t)Dc * Dc);     // 16*2304
    bf16* QKV   = (bf16*)(bc + (size_t)Bc * D3);         // 16*512*2304
    bf16* R     = QKV + (size_t)Bc * Nc * D3;            // reuse region
    bf16* Wc    = R;                                     // 16*2304*768 (phase 1)
    bf16* Vt    = R;                                     // 192*64*512  (phase 2)
    bf16* ctx   = R + (size_t)Bc * Hc * HDc * Nc;        // 16*512*768  (phase 2)

    dim3 blk(256);

    cast_bf16_kernel<<<(Bc * Nc * Dc / 8 + 255) / 256, blk, 0, stream>>>(x, x_bf, Bc * Nc * Dc / 8);
    cast_bf16_kernel<<<(Dc * Dc / 8 + 255) / 256, blk, 0, stream>>>(Wo, Wo_bf, Dc * Dc / 8);

    const float* Ws[3] = {Wq, Wk, Wv};
    const float* bs[3] = {bq, bk, bv};
    for (int t = 0; t < 3; ++t) {
        combine_w_kernel<<<(Dc * Dc / 4 + 255) / 256, blk, 0, stream>>>(g, Ws[t], Wc, t);
        combine_b_kernel<<<(Bc * Dc + 255) / 256, blk, 0, stream>>>(g, bs[t], bc, t);
    }

    // QKV = x_bf @ Wc^T + bc   (bf16 out), M=512 N=2304 K=768, z=batch
    gemm_mfma<128, 128, false, true, true, false><<<dim3(D3 / 128, Nc / 128, Bc), blk, 0, stream>>>(
        x_bf, Wc, QKV, bc, Dc, Dc, D3, Dc,
        (long)Nc * Dc, (long)D3 * Dc, (long)Nc * D3, D3);

    // attn = softmax(Q K^T / 8)  -> d_out (f32)
    scores_softmax_kernel<<<dim3(Nc / 64, Bc * Hc), blk, 0, stream>>>(QKV, attn);

    // Vt[z] = V[b,:,h-block]^T
    transpose_v_kernel<<<dim3(Nc / 64, Bc * Hc), blk, 0, stream>>>(QKV, Vt);

    // ctx[b,:,h-block] = attn[z] @ Vt[z]^T   (A = f32 attn, out bf16), M=512 N=64 K=512
    gemm_mfma<128, 64, true, true, false, true><<<dim3(1, Nc / 128, Bc * Hc), blk, 0, stream>>>(
        attn, Vt, ctx, nullptr, Nc, Nc, Dc, Nc,
        (long)Nc * Nc, (long)HDc * Nc, (long)Nc * Dc, 0);

    // out = ctx @ Wo^T + bo   (f32 out), M=512 N=768 K=768
    gemm_mfma<128, 128, false, false, true, false><<<dim3(Dc / 128, Nc / 128, Bc), blk, 0, stream>>>(
        ctx, Wo_bf, out, bo, Dc, Dc, Dc, Dc,
        (long)Nc * Dc, 0L, (long)Nc * Dc, 0);
}

// Round 3
// 264.205 us; speedup vs baseline: 3.2114x; 1.0893x over previous
//
#include <hip/hip_runtime.h>
#include <hip/hip_bf16.h>

#define Bc 16
#define Nc 512
#define Dc 768
#define Hc 12
#define Ec 8
#define HDc 64
#define D3 (3 * Dc)   // 2304

typedef __hip_bfloat16 bf16;
typedef short bf16x8 __attribute__((ext_vector_type(8)));     // 8 bf16, 4 VGPR
typedef float f32x4 __attribute__((ext_vector_type(4)));
typedef unsigned short u16x4 __attribute__((ext_vector_type(4)));

__device__ __forceinline__ unsigned short f2bf(float f) {
    union { __hip_bfloat16 h; unsigned short u; } cv;
    cv.h = __float2bfloat16(f);
    return cv.u;
}

__device__ __forceinline__ void gload16(const void* src, void* ldsDst) {
    __builtin_amdgcn_global_load_lds((const __attribute__((address_space(1))) void*)src,
                                     (__attribute__((address_space(3))) void*)ldsDst,
                                     16, 0, 0);
}

// ---------------- cast f32 -> bf16, 8 elems/thread ----------------
__global__ __launch_bounds__(256) void cast_bf16_kernel(const float* __restrict__ in,
                                                        bf16* __restrict__ out, int n8) {
    int i = blockIdx.x * 256 + threadIdx.x;
    if (i >= n8) return;
    f32x4 a = ((const f32x4*)in)[i * 2];
    f32x4 b = ((const f32x4*)in)[i * 2 + 1];
    unsigned short t[8];
#pragma unroll
    for (int j = 0; j < 4; ++j) { t[j] = f2bf(a[j]); t[4 + j] = f2bf(b[j]); }
    ((bf16x8*)out)[i] = *(bf16x8*)t;
}

// ---------------- gating fold: Wc[b][t*768+o][i] = sum_e g[b,e] W[e][o][i] (bf16 out) ----------------
__global__ __launch_bounds__(256) void combine_w_kernel(const float* __restrict__ g,
                                                        const float* __restrict__ W0,
                                                        const float* __restrict__ W1,
                                                        const float* __restrict__ W2,
                                                        bf16* __restrict__ Wc) {
    __shared__ float gs[Bc * Ec];
    int tid = threadIdx.x;
    if (tid < Bc * Ec) gs[tid] = g[tid];
    __syncthreads();
    int t = blockIdx.y;
    const float* W = (t == 0) ? W0 : ((t == 1) ? W1 : W2);
    const int P = Dc * Dc / 4;   // float4 positions
    int p = blockIdx.x * 256 + tid;
    if (p >= P) return;
    f32x4 w[Ec];
#pragma unroll
    for (int e = 0; e < Ec; ++e) w[e] = ((const f32x4*)W)[(size_t)e * P + p];
    int o = p / (Dc / 4), i4 = p - o * (Dc / 4);
#pragma unroll
    for (int b = 0; b < Bc; ++b) {
        f32x4 acc = {0.f, 0.f, 0.f, 0.f};
#pragma unroll
        for (int e = 0; e < Ec; ++e) {
            float ge = gs[b * Ec + e];
            acc[0] += ge * w[e][0]; acc[1] += ge * w[e][1];
            acc[2] += ge * w[e][2]; acc[3] += ge * w[e][3];
        }
        u16x4 ov;
#pragma unroll
        for (int j = 0; j < 4; ++j) ov[j] = f2bf(acc[j]);
        *(u16x4*)&Wc[((size_t)b * D3 + t * Dc + o) * Dc + i4 * 4] = ov;
    }
}

__global__ __launch_bounds__(256) void combine_b_kernel(const float* __restrict__ g,
                                                        const float* __restrict__ b0,
                                                        const float* __restrict__ b1,
                                                        const float* __restrict__ b2,
                                                        float* __restrict__ bc) {
    int t = blockIdx.y;
    const float* bvec = (t == 0) ? b0 : ((t == 1) ? b1 : b2);
    int i = blockIdx.x * 256 + threadIdx.x;
    if (i >= Bc * Dc) return;
    int b = i / Dc, o = i - b * Dc;
    float acc = 0.f;
#pragma unroll
    for (int e = 0; e < Ec; ++e) acc += g[b * Ec + e] * bvec[e * Dc + o];
    bc[(size_t)b * D3 + t * Dc + o] = acc;
}

// ---------------- bf16 MFMA NT GEMM: C[z] = A[z] * B[z]^T (+ bias) ----------------
// 256 threads = 4 waves (2x2), tile BM x BN, BK=32, 16x16x32 MFMA.
template<int BM, int BN, bool OUT_BF16, bool BIAS>
__global__ __launch_bounds__(256) void gemm_mfma(const bf16* __restrict__ Ain,
                                                 const bf16* __restrict__ Bin,
                                                 void* __restrict__ Cout,
                                                 const float* __restrict__ bias,
                                                 int lda, int ldb, int ldc, int K,
                                                 long sA, long sB, long sC, int sBias) {
    constexpr int A_LDS = BM * 64;
    constexpr int B_LDS = BN * 64;
    __shared__ __align__(16) char lds[A_LDS + B_LDS];
    char* ldsA = lds;
    char* ldsB = lds + A_LDS;

    const int tid = threadIdx.x;
    const int lane = tid & 63;
    const int wave = tid >> 6;
    const int wr = wave >> 1, wc = wave & 1;
    constexpr int TM = BM / 32;
    constexpr int TN = BN / 32;
    const int m0 = blockIdx.y * BM;
    const int n0 = blockIdx.x * BN;
    const int z = blockIdx.z;
    const int mbase = wr * (BM / 2);
    const int nbase = wc * (BN / 2);

    const bf16* Ab = Ain + (size_t)z * sA;
    const bf16* Bb = Bin + (size_t)z * sB;

    f32x4 acc[TM][TN];
#pragma unroll
    for (int m = 0; m < TM; ++m)
#pragma unroll
        for (int n = 0; n < TN; ++n) acc[m][n] = f32x4{0.f, 0.f, 0.f, 0.f};

    constexpr int ACH = BM / 64;   // 1024B LDS chunks per wave
    constexpr int BCH = BN / 64;

    for (int k0 = 0; k0 < K; k0 += 32) {
        // ---- stage A tile ----
#pragma unroll
        for (int c = 0; c < ACH; ++c) {
            int q = wave * ACH + c;
            int row = q * 16 + (lane >> 2);
            int sl = (lane & 3) ^ (row & 3);
            const bf16* src = Ab + (size_t)(m0 + row) * lda + k0 + sl * 8;
            gload16(src, ldsA + q * 1024);
        }
        // ---- stage B tile ----
#pragma unroll
        for (int c = 0; c < BCH; ++c) {
            int q = wave * BCH + c;
            int row = q * 16 + (lane >> 2);
            int sl = (lane & 3) ^ (row & 3);
            const bf16* src = Bb + (size_t)(n0 + row) * ldb + k0 + sl * 8;
            gload16(src, ldsB + q * 1024);
        }
        __syncthreads();

        bf16x8 af[TM], bfr[TN];
#pragma unroll
        for (int m = 0; m < TM; ++m) {
            int r = mbase + m * 16 + (lane & 15);
            int sp = (lane >> 4) ^ (lane & 3);       // == (lane>>4) ^ (r&3)
            af[m] = *(const bf16x8*)(ldsA + r * 64 + sp * 16);
        }
#pragma unroll
        for (int n = 0; n < TN; ++n) {
            int r = nbase + n * 16 + (lane & 15);
            int sp = (lane >> 4) ^ (lane & 3);
            bfr[n] = *(const bf16x8*)(ldsB + r * 64 + sp * 16);
        }
#pragma unroll
        for (int m = 0; m < TM; ++m)
#pragma unroll
            for (int n = 0; n < TN; ++n)
                acc[m][n] = __builtin_amdgcn_mfma_f32_16x16x32_bf16(af[m], bfr[n], acc[m][n], 0, 0, 0);
        __syncthreads();
    }

    // ---- epilogue ----
    size_t cOff = (size_t)z * sC;
#pragma unroll
    for (int n = 0; n < TN; ++n) {
        int col = n0 + nbase + n * 16 + (lane & 15);
        float bv = 0.f;
        if constexpr (BIAS) bv = bias[(size_t)z * sBias + col];
#pragma unroll
        for (int m = 0; m < TM; ++m) {
            int row = m0 + mbase + m * 16 + (lane >> 4) * 4;
#pragma unroll
            for (int r = 0; r < 4; ++r) {
                float val = acc[m][n][r] + bv;
                if constexpr (OUT_BF16)
                    ((bf16*)Cout)[cOff + (size_t)(row + r) * ldc + col] = __float2bfloat16(val);
                else
                    ((float*)Cout)[cOff + (size_t)(row + r) * ldc + col] = val;
            }
        }
    }
}

// ---------------- Vt[z][d][k] = V[b][k][1536 + h*64 + d] (bf16) ----------------
__global__ __launch_bounds__(256) void transpose_v_kernel(const bf16* __restrict__ QKV,
                                                          bf16* __restrict__ Vt) {
    int z = blockIdx.y;
    int b = z / Hc, h = z - b * Hc;
    int k0 = blockIdx.x * 64;
    __shared__ bf16 t[64][72];
    const bf16* src = QKV + ((size_t)b * Nc + k0) * D3 + 2 * Dc + h * HDc;
#pragma unroll
    for (int it = 0; it < 2; ++it) {
        int idx = it * 256 + threadIdx.x;   // 0..511
        int r = idx >> 3, cg = idx & 7;
        bf16x8 v = *(const bf16x8*)(src + (size_t)r * D3 + cg * 8);
#pragma unroll
        for (int j = 0; j < 8; ++j) t[r][cg * 8 + j] = ((const bf16*)&v)[j];
    }
    __syncthreads();
    bf16* dst = Vt + (size_t)z * HDc * Nc + k0;
#pragma unroll
    for (int it = 0; it < 2; ++it) {
        int idx = it * 256 + threadIdx.x;
        int d = idx >> 3, kg = idx & 7;
        bf16 tmp[8];
#pragma unroll
        for (int j = 0; j < 8; ++j) tmp[j] = t[kg * 8 + j][d];
        *(bf16x8*)(dst + (size_t)d * Nc + kg * 8) = *(bf16x8*)tmp;
    }
}

// ---------------- fused: attn[z] = softmax(Q K^T / 8); ctx = attn @ V ----------------
// grid (8 q-tiles, 192 bh). Block 256 = 4 waves; each wave owns 16 q-rows x all 512 k.
__global__ __launch_bounds__(256) void fused_attn_kernel(const bf16* __restrict__ QKV,
                                                         const bf16* __restrict__ Vt,
                                                         float* __restrict__ attn,
                                                         bf16* __restrict__ ctx) {
    __shared__ __align__(16) char plds[64 * 1024];   // P tile [64][512] bf16, XOR-swizzled
    int z = blockIdx.y;
    int b = z / Hc, h = z - b * Hc;
    int wave = threadIdx.x >> 6, lane = threadIdx.x & 63;
    int qbase = blockIdx.x * 64 + wave * 16;
    const bf16* Qb = QKV + (size_t)b * Nc * D3 + h * HDc;
    const bf16* Kb = Qb + Dc;
    int kq = (lane >> 4) * 8;
    int cl = lane & 15;
    int rl = (lane >> 4) * 4;

    bf16x8 qf0 = *(const bf16x8*)(Qb + (size_t)(qbase + cl) * D3 + kq);
    bf16x8 qf1 = *(const bf16x8*)(Qb + (size_t)(qbase + cl) * D3 + 32 + kq);

    f32x4 acc[32];
#pragma unroll
    for (int n = 0; n < 32; ++n) {
        int krow = n * 16 + cl;
        bf16x8 k0 = *(const bf16x8*)(Kb + (size_t)krow * D3 + kq);
        bf16x8 k1 = *(const bf16x8*)(Kb + (size_t)krow * D3 + 32 + kq);
        f32x4 a = {0.f, 0.f, 0.f, 0.f};
        a = __builtin_amdgcn_mfma_f32_16x16x32_bf16(qf0, k0, a, 0, 0, 0);
        a = __builtin_amdgcn_mfma_f32_16x16x32_bf16(qf1, k1, a, 0, 0, 0);
        acc[n] = a;
    }

    const float sc = 0.125f;
    float mx[4] = {-1e30f, -1e30f, -1e30f, -1e30f};
#pragma unroll
    for (int n = 0; n < 32; ++n)
#pragma unroll
        for (int r = 0; r < 4; ++r) {
            acc[n][r] *= sc;
            mx[r] = fmaxf(mx[r], acc[n][r]);
        }
#pragma unroll
    for (int off = 8; off >= 1; off >>= 1)
#pragma unroll
        for (int r = 0; r < 4; ++r) mx[r] = fmaxf(mx[r], __shfl_xor(mx[r], off));

    float sum[4] = {0.f, 0.f, 0.f, 0.f};
#pragma unroll
    for (int n = 0; n < 32; ++n)
#pragma unroll
        for (int r = 0; r < 4; ++r) {
            float e = __expf(acc[n][r] - mx[r]);
            acc[n][r] = e;
            sum[r] += e;
        }
#pragma unroll
    for (int off = 8; off >= 1; off >>= 1)
#pragma unroll
        for (int r = 0; r < 4; ++r) sum[r] += __shfl_xor(sum[r], off);
    float inv[4];
#pragma unroll
    for (int r = 0; r < 4; ++r) inv[r] = 1.0f / sum[r];

    // write attn (f32, required output) + P tile to LDS (bf16, swizzled)
    float* arow = attn + (size_t)z * Nc * Nc + (size_t)qbase * Nc;
#pragma unroll
    for (int n = 0; n < 32; ++n)
#pragma unroll
        for (int r = 0; r < 4; ++r) {
            float p = acc[n][r] * inv[r];
            arow[(size_t)(rl + r) * Nc + n * 16 + cl] = p;
            int row = wave * 16 + rl + r;
            int colb = (n * 16 + cl) * 2;
            *(bf16*)(plds + row * 1024 + (colb ^ ((row & 7) << 4))) = __float2bfloat16(p);
        }
    __syncthreads();

    // PV: ctx[q][d] = sum_k P[q][k] * V[k][d], P from own LDS rows, Vt rows from L2
    const bf16* Vtb = Vt + (size_t)z * HDc * Nc;
    f32x4 o4[4];
#pragma unroll
    for (int d0 = 0; d0 < 4; ++d0) o4[d0] = f32x4{0.f, 0.f, 0.f, 0.f};
    int prow = wave * 16 + cl;
    const char* pbase = plds + prow * 1024;
    int pswz = (prow & 7) << 4;
#pragma unroll
    for (int ks = 0; ks < 16; ++ks) {
        int k0 = ks * 32;
        bf16x8 pa = *(const bf16x8*)(pbase + (((k0 + kq) * 2) ^ pswz));
#pragma unroll
        for (int d0 = 0; d0 < 4; ++d0) {
            bf16x8 vb = *(const bf16x8*)(Vtb + (size_t)(d0 * 16 + cl) * Nc + k0 + kq);
            o4[d0] = __builtin_amdgcn_mfma_f32_16x16x32_bf16(pa, vb, o4[d0], 0, 0, 0);
        }
    }
    bf16* cb = ctx + ((size_t)b * Nc + qbase + rl) * Dc + h * HDc;
#pragma unroll
    for (int d0 = 0; d0 < 4; ++d0)
#pragma unroll
        for (int r = 0; r < 4; ++r)
            cb[(size_t)r * Dc + d0 * 16 + cl] = __float2bfloat16(o4[d0][r]);
}

extern "C" void kernel_launch(void* const* d_in, const int* in_sizes, int n_in,
                              void* d_out, int out_size, void* d_ws, size_t ws_size,
                              hipStream_t stream) {
    (void)in_sizes; (void)n_in; (void)out_size; (void)ws_size;
    const float* x  = (const float*)d_in[0];
    const float* g  = (const float*)d_in[1];
    const float* Wq = (const float*)d_in[2];
    const float* bq = (const float*)d_in[3];
    const float* Wk = (const float*)d_in[4];
    const float* bk = (const float*)d_in[5];
    const float* Wv = (const float*)d_in[6];
    const float* bv = (const float*)d_in[7];
    const float* Wo = (const float*)d_in[8];
    const float* bo = (const float*)d_in[9];

    float* out  = (float*)d_out;
    float* attn = out + (size_t)Bc * Nc * Dc;

    // workspace layout: x_bf | Wo_bf | bc | QKV | R{Wc -> Vt,ctx}
    char* w = (char*)d_ws;
    bf16* x_bf  = (bf16*)w;                              // 16*512*768
    bf16* Wo_bf = x_bf + (size_t)Bc * Nc * Dc;           // 768*768
    float* bc   = (float*)(Wo_bf + (size_t)Dc * Dc);     // 16*2304
    bf16* QKV   = (bf16*)(bc + (size_t)Bc * D3);         // 16*512*2304
    bf16* R     = QKV + (size_t)Bc * Nc * D3;            // reuse region
    bf16* Wc    = R;                                     // 16*2304*768 (phase 1)
    bf16* Vt    = R;                                     // 192*64*512  (phase 2)
    bf16* ctx   = R + (size_t)Bc * Hc * HDc * Nc;        // 16*512*768  (phase 2)

    dim3 blk(256);

    cast_bf16_kernel<<<(Bc * Nc * Dc / 8 + 255) / 256, blk, 0, stream>>>(x, x_bf, Bc * Nc * Dc / 8);
    cast_bf16_kernel<<<(Dc * Dc / 8 + 255) / 256, blk, 0, stream>>>(Wo, Wo_bf, Dc * Dc / 8);

    combine_w_kernel<<<dim3((Dc * Dc / 4 + 255) / 256, 3), blk, 0, stream>>>(g, Wq, Wk, Wv, Wc);
    combine_b_kernel<<<dim3((Bc * Dc + 255) / 256, 3), blk, 0, stream>>>(g, bq, bk, bv, bc);

    // QKV = x_bf @ Wc^T + bc   (bf16 out), M=512 N=2304 K=768, z=batch
    gemm_mfma<128, 128, true, true><<<dim3(D3 / 128, Nc / 128, Bc), blk, 0, stream>>>(
        x_bf, Wc, QKV, bc, Dc, Dc, D3, Dc,
        (long)Nc * Dc, (long)D3 * Dc, (long)Nc * D3, D3);

    // Vt[z] = V[b,:,h-block]^T
    transpose_v_kernel<<<dim3(Nc / 64, Bc * Hc), blk, 0, stream>>>(QKV, Vt);

    // attn (to d_out) + ctx = attn @ V  fused
    fused_attn_kernel<<<dim3(Nc / 64, Bc * Hc), blk, 0, stream>>>(QKV, Vt, attn, ctx);

    // out = ctx @ Wo^T + bo   (f32 out), M=512 N=768 K=768
    gemm_mfma<128, 128, false, true><<<dim3(Dc / 128, Nc / 128, Bc), blk, 0, stream>>>(
        ctx, Wo_bf, out, bo, Dc, Dc, Dc, Dc,
        (long)Nc * Dc, 0L, (long)Nc * Dc, 0);
}